// Round 4
// baseline (412.421 us; speedup 1.0000x reference)
//
#include <hip/hip_runtime.h>

// Problem constants
#define N_NODES   300000
#define K_STENCIL 27
#define CIN       32
#define COUT      64
#define BN_EPS    1e-5f

// Workspace layout (bytes):
//   [0, 32768)           : split stats, 64 splits x (sum[64], sumsq[64]) fp32
//   [32768, 33280)       : ab coeffs a[64], b[64] fp32
//   [33280, 33280+110592): weightT bf16 [27][64][32] (ushort)
#define WS_STATS_OFF 0
#define WS_AB_OFF    32768
#define WS_WT_OFF    33280
#define N_SPLITS     64

typedef short bf16x8 __attribute__((ext_vector_type(8)));
typedef float f32x4  __attribute__((ext_vector_type(4)));

__device__ __forceinline__ short f2bf_rne(float f) {
    unsigned u = __builtin_bit_cast(unsigned, f);
    u += 0x7fffu + ((u >> 16) & 1u);   // round-to-nearest-even
    return (short)(u >> 16);
}

// ---------------------------------------------------------------------------
// zero the split-stats accumulators (ws is poisoned before every launch)
// 64 splits x 128 floats = 8192 floats; 32 blocks x 256 threads.
// ---------------------------------------------------------------------------
__global__ void zero_stats(float* __restrict__ stats) {
    stats[blockIdx.x * blockDim.x + threadIdx.x] = 0.f;
}

// ---------------------------------------------------------------------------
// weight [27][32][64] fp32 -> weightT [27][64][32] bf16 (RNE)
// ---------------------------------------------------------------------------
__global__ void prep_weight(const float* __restrict__ w, unsigned short* __restrict__ wT) {
    int t = blockIdx.x * blockDim.x + threadIdx.x;   // 27*64*32 = 55296
    if (t >= K_STENCIL * COUT * CIN) return;
    int c = t & (CIN - 1);
    int o = (t >> 5) & (COUT - 1);
    int k = t >> 11;
    wT[t] = (unsigned short)f2bf_rne(w[(k * CIN + c) * COUT + o]);
}

// ---------------------------------------------------------------------------
// Gather-GEMM via MFMA. Block = 256 = 4 waves; each wave: 16 nodes x 64 couts.
// A packing: node at slot lane&15, channel at slot quad*8+j (any consistent
//            k-permutation cancels between A and B).
// B packing: cout at slot ct*16 + (lane&15), channel at slot quad*8+j.
// C/D layout: SELF-DISCOVERED at runtime via a probe MFMA D = I*T with
//            T[k][n] = k*16+n -> slot value encodes (m,n) directly. Robust to
//            any C/D register mapping (the R1 failure signature pointed here).
// neigh is int32 on device (harness converts; int64 read caused R2/R3 faults).
// ---------------------------------------------------------------------------
__global__ __launch_bounds__(256) void conv_mfma(
        const float* __restrict__ data, const int* __restrict__ neigh,
        const unsigned short* __restrict__ wT, float* __restrict__ out) {
    const int wave  = threadIdx.x >> 6;
    const int lane  = threadIdx.x & 63;
    const int row16 = lane & 15;
    const int quad  = lane >> 4;

    // ---- layout probe ----
    bf16x8 ia, tb;
    #pragma unroll
    for (int j = 0; j < 8; ++j) {
        int k = quad * 8 + j;
        ia[j] = (k == row16) ? (short)0x3F80 : (short)0;       // I[m][k]
        tb[j] = f2bf_rne((float)(k * 16 + row16));             // T[k][n], n=row16
    }
    f32x4 pacc = {0.f, 0.f, 0.f, 0.f};
    pacc = __builtin_amdgcn_mfma_f32_16x16x32_bf16(ia, tb, pacc, 0, 0, 0);
    int mrow[4], ncol[4];
    #pragma unroll
    for (int r = 0; r < 4; ++r) {
        int iv = (int)(pacc[r] + 0.5f);
        mrow[r] = (iv >> 4) & 15;   // true node-sub-index held by this slot
        ncol[r] = iv & 15;          // true cout-sub-index held by this slot
    }

    // ---- main gather-GEMM ----
    const int node   = blockIdx.x * 64 + wave * 16 + row16;
    const bool valid = (node < N_NODES);
    const int nclamp = valid ? node : 0;

    f32x4 acc[4] = {f32x4{0,0,0,0}, f32x4{0,0,0,0}, f32x4{0,0,0,0}, f32x4{0,0,0,0}};
    const int* nrow = neigh + nclamp * K_STENCIL;

    #pragma unroll 3
    for (int k = 0; k < K_STENCIL; ++k) {
        int idx = nrow[k];
        bf16x8 afrag;
        if (valid && idx >= 0) {
            const f32x4* drow = (const f32x4*)(data + (size_t)idx * CIN + quad * 8);
            f32x4 lo = drow[0];
            f32x4 hi = drow[1];
            #pragma unroll
            for (int j = 0; j < 4; ++j) {
                afrag[j]     = f2bf_rne(lo[j]);
                afrag[j + 4] = f2bf_rne(hi[j]);
            }
        } else {
            afrag = bf16x8{0,0,0,0,0,0,0,0};
        }
        const unsigned short* wk = wT + k * (COUT * CIN) + row16 * CIN + quad * 8;
        #pragma unroll
        for (int ct = 0; ct < 4; ++ct) {
            bf16x8 bfrag = *(const bf16x8*)(wk + ct * 16 * CIN);
            acc[ct] = __builtin_amdgcn_mfma_f32_16x16x32_bf16(afrag, bfrag, acc[ct], 0, 0, 0);
        }
    }

    // ---- epilogue: write with the discovered (m,n) mapping ----
    const int tilebase = blockIdx.x * 64 + wave * 16;
    #pragma unroll
    for (int ct = 0; ct < 4; ++ct) {
        #pragma unroll
        for (int r = 0; r < 4; ++r) {
            int n_out = tilebase + mrow[r];
            if (n_out < N_NODES)
                out[(size_t)n_out * COUT + ct * 16 + ncol[r]] = acc[ct][r];
        }
    }
}

// ---------------------------------------------------------------------------
// BN stats over out[N][64]: coalesced float4 sweep, per-block LDS reduce,
// split global atomics. Orientation-independent of the conv epilogue.
// ---------------------------------------------------------------------------
__global__ __launch_bounds__(256) void stats_pass(const float* __restrict__ out,
                                                  float* __restrict__ stats) {
    __shared__ float lsum[COUT];
    __shared__ float lsq[COUT];
    if (threadIdx.x < COUT) { lsum[threadIdx.x] = 0.f; lsq[threadIdx.x] = 0.f; }
    __syncthreads();

    const int j = threadIdx.x & 15;                 // float4 column group (fixed)
    int row = blockIdx.x * 16 + (threadIdx.x >> 4);
    const int rstride = gridDim.x * 16;
    float s0=0,s1=0,s2=0,s3=0,q0=0,q1=0,q2=0,q3=0;
    for (; row < N_NODES; row += rstride) {
        f32x4 v = ((const f32x4*)out)[row * 16 + j];
        s0 += v[0]; q0 += v[0]*v[0];
        s1 += v[1]; q1 += v[1]*v[1];
        s2 += v[2]; q2 += v[2]*v[2];
        s3 += v[3]; q3 += v[3]*v[3];
    }
    atomicAdd(&lsum[j*4+0], s0); atomicAdd(&lsq[j*4+0], q0);
    atomicAdd(&lsum[j*4+1], s1); atomicAdd(&lsq[j*4+1], q1);
    atomicAdd(&lsum[j*4+2], s2); atomicAdd(&lsq[j*4+2], q2);
    atomicAdd(&lsum[j*4+3], s3); atomicAdd(&lsq[j*4+3], q3);
    __syncthreads();

    if (threadIdx.x < 128) {
        int split = blockIdx.x & (N_SPLITS - 1);
        float v = (threadIdx.x < 64) ? lsum[threadIdx.x] : lsq[threadIdx.x - 64];
        atomicAdd(&stats[split * 128 + threadIdx.x], v);
    }
}

// ---------------------------------------------------------------------------
// fold stats + gamma/beta into per-channel affine a,b
// ---------------------------------------------------------------------------
__global__ void finalize_stats(const float* __restrict__ stats,
                               const float* __restrict__ gamma,
                               const float* __restrict__ beta,
                               float* __restrict__ ab) {
    int o = threadIdx.x;  // 64 threads
    if (o >= COUT) return;
    float s = 0.f, q = 0.f;
    for (int sp = 0; sp < N_SPLITS; ++sp) {
        s += stats[sp * 128 + o];
        q += stats[sp * 128 + 64 + o];
    }
    float inv_n = 1.0f / (float)N_NODES;
    float mean = s * inv_n;
    float var  = q * inv_n - mean * mean;
    float a = gamma[o] * rsqrtf(var + BN_EPS);
    float b = beta[o] - mean * a;
    ab[o] = a;
    ab[64 + o] = b;
}

// ---------------------------------------------------------------------------
// y = relu(x * a[o] + b[o]), in place on d_out, float4, exact grid
// ---------------------------------------------------------------------------
__global__ __launch_bounds__(256) void bn_relu(float* __restrict__ out,
                                               const float* __restrict__ ab) {
    int i = blockIdx.x * blockDim.x + threadIdx.x;  // float4 index
    f32x4 a = ((const f32x4*)ab)[i & 15];
    f32x4 b = ((const f32x4*)(ab + 64))[i & 15];
    f32x4 v = ((f32x4*)out)[i];
    #pragma unroll
    for (int j = 0; j < 4; ++j) {
        float y = v[j] * a[j] + b[j];
        v[j] = y > 0.f ? y : 0.f;
    }
    ((f32x4*)out)[i] = v;
}

// ---------------------------------------------------------------------------
extern "C" void kernel_launch(void* const* d_in, const int* in_sizes, int n_in,
                              void* d_out, int out_size, void* d_ws, size_t ws_size,
                              hipStream_t stream) {
    const float* data   = (const float*)d_in[0];
    const int*   neigh  = (const int*)d_in[1];     // int32 on device
    const float* weight = (const float*)d_in[2];
    const float* gamma  = (const float*)d_in[3];
    const float* beta   = (const float*)d_in[4];
    float* out = (float*)d_out;

    char* ws = (char*)d_ws;
    float*          stats = (float*)(ws + WS_STATS_OFF);
    float*          ab    = (float*)(ws + WS_AB_OFF);
    unsigned short* wT    = (unsigned short*)(ws + WS_WT_OFF);

    zero_stats<<<32, 256, 0, stream>>>(stats);
    prep_weight<<<(K_STENCIL * COUT * CIN + 255) / 256, 256, 0, stream>>>(weight, wT);

    int grid = (N_NODES + 63) / 64;  // 4688
    conv_mfma<<<grid, 256, 0, stream>>>(data, neigh, wT, out);

    stats_pass<<<1024, 256, 0, stream>>>(out, stats);
    finalize_stats<<<1, 64, 0, stream>>>(stats, gamma, beta, ab);

    int total4 = N_NODES * COUT / 4;  // 4,800,000
    bn_relu<<<total4 / 256, 256, 0, stream>>>(out, ab);
}